// Round 15
// baseline (87.275 us; speedup 1.0000x reference)
//
#include <hip/hip_runtime.h>
#include <stdint.h>

// SSIM fused kernel v15, MI355X (gfx950).
// v14 post-mortem: WIN (84.5->73us). VALU-issue bound (68% busy, occ pinned,
// HBM 16%). v15: pass-1 packs across COLUMN PAIRS so all 5 streams are
// v_pk_* (v14 left pt scalar): 131 math-ops/col vs 160 (-18%).
//  - Pass-1 items: 38 col-pairs x 4-row groups = 152; mapping pair=lane
//    (38/64 active), rowgroup=wave -> every wave/SIMD gets exactly 1 item
//    (v14: wave 0 did 2 items = stage critical path).
//  - Pass-1 reads: 28 ds_read_b64 (float2, even-aligned via COFF=2);
//    writes: contiguous uint4/float2 (conflict-free).
//  - Halo widened to 76 cols (c'=0..75, cols 0 and 75 dead but staged-zero
//    safe); pass-2 reads 8 uint4 covering window c'=cb+1..cb+14.
//  - Everything else = v14: stage-0 f32 staging (SW=84), RTN fp16 rbAB +
//    f32 rbC, packed-f32 pass-2, 2-kernel deterministic mean.

#define HH 512
#define WW 512
#define PLANES 48
#define TW 64
#define TH 16
#define RR 5
#define KK 11
#define IN_H (TH + 2 * RR)        // 26 halo rows
#define SW 84                      // sp/st row stride (staged x0-8..x0+71)
#define COFF 2                     // halo col c' (global x0-6+c') -> staged c'+2
#define NPAIR 38                   // col pairs (76 halo cols)
#define RBW 76                     // rb row stride (uint2 / float)
#define NBLOCKS (PLANES * (WW / TW) * (HH / TH))  // 12288
#define NTHREADS 256
#define NSTAGE (IN_H * 20)        // 520 staging granules
#define TOTAL_ELEMS (PLANES * HH * WW)

typedef _Float16 half2v __attribute__((ext_vector_type(2)));
typedef float float2v __attribute__((ext_vector_type(2)));

constexpr float G_[KK] = {
    1.4867195147342977e-06f, 1.3383022576488537e-04f, 4.4318484119380075e-03f,
    5.3990966513188063e-02f, 2.4197072451914337e-01f, 3.9894228040143270e-01f,
    2.4197072451914337e-01f, 5.3990966513188063e-02f, 4.4318484119380075e-03f,
    1.3383022576488537e-04f, 1.4867195147342977e-06f};

__device__ __forceinline__ half2v u2h(uint32_t u) {
  return __builtin_bit_cast(half2v, u);
}
// RTN fp16 pack — unbiased (v4/v8 verified; RTZ pack is NOT safe, v7).
__device__ __forceinline__ uint32_t packrtn(float a, float b) {
  half2v h = {(_Float16)a, (_Float16)b};
  return __builtin_bit_cast(uint32_t, h);
}

__global__ __launch_bounds__(NTHREADS, 4) void ssim_tile_kernel(
    const float* __restrict__ pred, const float* __restrict__ targ,
    float* __restrict__ partial) {
  __shared__ __align__(16) float sp[IN_H][SW];     // 8.7 KB raw pred
  __shared__ __align__(16) float st[IN_H][SW];     // 8.7 KB raw targ
  __shared__ __align__(16) uint2 rbAB[TH][RBW];    // 9.5 KB {pk(p,t),pk(pp,tt)}
  __shared__ __align__(16) float rbC[TH][RBW];     // 4.75 KB vconv_pt f32
  __shared__ float wsums[4];

  const int tid = threadIdx.x;
  const int bid = blockIdx.x;
  const int plane = bid >> 8;
  const int tile = bid & 255;
  const int x0 = (tile & 7) * TW;
  const int y0 = (tile >> 3) * TH;
  const float* pp = pred + (size_t)plane * (HH * WW);
  const float* tp = targ + (size_t)plane * (HH * WW);

  // ---- Stage 0: stage raw halo (granule-aligned float4, uniform path) ----
  for (int i = tid; i < NSTAGE; i += NTHREADS) {
    const int r = i / 20;            // halo row 0..25
    const int cg = i - r * 20;       // granule 0..19
    const int gy = y0 + r - RR;
    const int gx = x0 - 8 + cg * 4;  // granule start, 16B aligned
    float4 pv = make_float4(0.f, 0.f, 0.f, 0.f);
    float4 tv = pv;
    if (gy >= 0 && gy < HH && gx >= 0 && gx <= WW - 4) {
      const int o = gy * WW + gx;
      pv = *reinterpret_cast<const float4*>(pp + o);
      tv = *reinterpret_cast<const float4*>(tp + o);
    }
    *reinterpret_cast<float4*>(&sp[r][cg * 4]) = pv;
    *reinterpret_cast<float4*>(&st[r][cg * 4]) = tv;
  }
  __syncthreads();

  // ---- Pass 1: VERTICAL conv, col-pair items, all-pk math ----
  {
    const int l = tid & 63;          // lane: col pair 0..37 (38 active)
    const int rg = tid >> 6;         // wave: row group 0..3
    if (l < NPAIR) {
      const int yb = rg * 4;         // output rows yb..yb+3
      const int sc = 2 * l + COFF;   // staged col of c'=2l (even -> b64 ok)

      float2v P[14], T[14];
#pragma unroll
      for (int m = 0; m < 14; ++m) {
        P[m] = *reinterpret_cast<const float2v*>(&sp[yb + m][sc]);
        T[m] = *reinterpret_cast<const float2v*>(&st[yb + m][sc]);
      }

      // Scatter: input row-position q (0..13) feeds outputs j in
      // [max(0,q-10), min(3,q)] with weight G_[q-j]. 5 pk streams.
      float2v sP[4]  = {{0,0},{0,0},{0,0},{0,0}};
      float2v sT[4]  = {{0,0},{0,0},{0,0},{0,0}};
      float2v sPP[4] = {{0,0},{0,0},{0,0},{0,0}};
      float2v sTT[4] = {{0,0},{0,0},{0,0},{0,0}};
      float2v sPT[4] = {{0,0},{0,0},{0,0},{0,0}};
#pragma unroll
      for (int q = 0; q < 14; ++q) {
        const float2v Pq = P[q], Tq = T[q];
        const float2v PPq = Pq * Pq;   // v_pk_mul_f32
        const float2v TTq = Tq * Tq;
        const float2v PTq = Pq * Tq;
#pragma unroll
        for (int j = 0; j < 4; ++j) {
          if (q < j || q > j + 10) continue;
          const float w = G_[q - j];
          const float2v w2 = {w, w};
          sP[j]  = __builtin_elementwise_fma(w2, Pq,  sP[j]);   // v_pk_fma_f32
          sT[j]  = __builtin_elementwise_fma(w2, Tq,  sT[j]);
          sPP[j] = __builtin_elementwise_fma(w2, PPq, sPP[j]);
          sTT[j] = __builtin_elementwise_fma(w2, TTq, sTT[j]);
          sPT[j] = __builtin_elementwise_fma(w2, PTq, sPT[j]);
        }
      }

#pragma unroll
      for (int j = 0; j < 4; ++j) {
        uint4 wv;                      // cols c'=2l, 2l+1 interleaved {A,B}
        wv.x = packrtn(sP[j].x,  sT[j].x);
        wv.y = packrtn(sPP[j].x, sTT[j].x);
        wv.z = packrtn(sP[j].y,  sT[j].y);
        wv.w = packrtn(sPP[j].y, sTT[j].y);
        *reinterpret_cast<uint4*>(&rbAB[yb + j][2 * l]) = wv;   // 16B contig
        float2v c2 = {sPT[j].x, sPT[j].y};
        *reinterpret_cast<float2v*>(&rbC[yb + j][2 * l]) = c2;  // 8B contig
      }
    }
  }
  __syncthreads();

  // ---- Pass 2: HORIZONTAL conv (packed f32) + SSIM map; 256 items exact --
  float lsum = 0.f;
  {
    const int m = tid & 15;          // col group 0..15
    const int y = tid >> 4;          // output row 0..15
    const int cb = m << 2;           // outputs cb..cb+3; window c' cb+1..cb+14

    uint2 qv[16];
#pragma unroll
    for (int h = 0; h < 8; ++h) {
      uint4 w = *reinterpret_cast<const uint4*>(&rbAB[y][cb + 2 * h]);
      qv[2*h]   = make_uint2(w.x, w.y);
      qv[2*h+1] = make_uint2(w.z, w.w);
    }
    float cv[16];
#pragma unroll
    for (int h = 0; h < 4; ++h) {
      *reinterpret_cast<float4*>(&cv[4*h]) =
          *reinterpret_cast<const float4*>(&rbC[y][cb + 4 * h]);
    }

    float2v fa[14], fb[14];          // fa[k] <-> c' = cb+1+k
#pragma unroll
    for (int k = 0; k < 14; ++k) {
      half2v ha = u2h(qv[k + 1].x), hb = u2h(qv[k + 1].y);
      fa[k] = float2v{(float)ha.x, (float)ha.y};
      fb[k] = float2v{(float)hb.x, (float)hb.y};
    }

    float2v accA[4], accB[4];
    float sC[4];
#pragma unroll
    for (int j = 0; j < 4; ++j) {
      float2v a = {0, 0}, b = {0, 0};
      float c = 0.f;
#pragma unroll
      for (int k = 0; k < KK; ++k) {
        const float2v w2 = {G_[k], G_[k]};
        a = __builtin_elementwise_fma(w2, fa[j + k], a);
        b = __builtin_elementwise_fma(w2, fb[j + k], b);
        c = fmaf(G_[k], cv[j + 1 + k], c);
      }
      accA[j] = a; accB[j] = b; sC[j] = c;
    }

    const float C1 = 1.0e-4f;
    const float C2 = 9.0e-4f;
#pragma unroll
    for (int j = 0; j < 4; ++j) {
      const float mu_x = accA[j].x;
      const float mu_y = accA[j].y;
      const float2v sv = __builtin_elementwise_fma(-accA[j], accA[j], accB[j]);
      const float sxy = sC[j] - mu_x * mu_y;
      const float num = (2.f * mu_x * mu_y + C1) * (2.f * sxy + C2);
      const float den = (mu_x * mu_x + mu_y * mu_y + C1) *
                        (fmaf(sv.x, sv.x, fmaf(sv.y, sv.y, C2)));
      lsum = fmaf(num, __builtin_amdgcn_rcpf(den), lsum);
    }
  }

  // ---- Block reduction -> partial[bid] ----
#pragma unroll
  for (int off = 32; off > 0; off >>= 1) lsum += __shfl_xor(lsum, off, 64);
  if ((tid & 63) == 0) wsums[tid >> 6] = lsum;
  __syncthreads();
  if (tid == 0)
    partial[bid] = (wsums[0] + wsums[1]) + (wsums[2] + wsums[3]);
}

__global__ __launch_bounds__(1024) void ssim_reduce_kernel(
    const float* __restrict__ partial, float* __restrict__ out) {
  float s = 0.f;
  for (int i = threadIdx.x; i < NBLOCKS; i += 1024) s += partial[i];
#pragma unroll
  for (int off = 32; off > 0; off >>= 1) s += __shfl_xor(s, off, 64);
  __shared__ float ws[16];
  if ((threadIdx.x & 63) == 0) ws[threadIdx.x >> 6] = s;
  __syncthreads();
  if (threadIdx.x == 0) {
    float t = 0.f;
#pragma unroll
    for (int i = 0; i < 16; ++i) t += ws[i];
    out[0] = t * (1.0f / (float)TOTAL_ELEMS);
  }
}

extern "C" void kernel_launch(void* const* d_in, const int* in_sizes, int n_in,
                              void* d_out, int out_size, void* d_ws,
                              size_t ws_size, hipStream_t stream) {
  const float* pred = (const float*)d_in[0];
  const float* targ = (const float*)d_in[1];
  float* out = (float*)d_out;
  float* partial = (float*)d_ws;

  ssim_tile_kernel<<<NBLOCKS, NTHREADS, 0, stream>>>(pred, targ, partial);
  ssim_reduce_kernel<<<1, 1024, 0, stream>>>(partial, out);
}

// Round 16
// 73.849 us; speedup vs baseline: 1.1818x; 1.1818x over previous
//
#include <hip/hip_runtime.h>
#include <stdint.h>

// SSIM fused kernel v16, MI355X (gfx950).
// v15 post-mortem: col-pair packing REGRESSED (73->90us): conflicts tripled
// (stride-2-word b64 reads) + 38/64 lane activity. Lesson: never trade LDS
// access pattern / lane occupancy for op count. Reverted to v14 base.
// v16 = v14 + two pattern-preserving cuts:
//  - TAP TRUNCATION: Gaussian edge taps G[0]=G[10]=1.49e-6 dropped in both
//    passes (taps 1..9, exact reference weights). Bias analysis calibrated
//    on the v7 RTZ incident: predicted mean shift ~7e-4 < 2.58e-3 threshold.
//    -18% conv FMAs, -4 LDS reads per pass-1 item. Zero mapping changes.
//  - Stage-0 interior fast path (block-uniform branch, ~70% of blocks):
//    unconditional loads, no per-granule guards.
// Kept: col-first separable order, stage-0 f32 staging (SW=84), packed-f32
// math, RTN fp16 rbAB + f32 rbC, 2-kernel deterministic mean.

#define HH 512
#define WW 512
#define PLANES 48
#define TW 64
#define TH 16
#define RR 5
#define IN_H (TH + 2 * RR)        // 26 halo rows
#define HALO_W 74                  // halo cols used (x0-5 .. x0+68)
#define SW 84                      // sp/st row stride (staged x0-8..x0+71)
#define COFF 3                     // halo col c -> staged col c+3
#define RBW 76                     // rb row stride
#define NBLOCKS (PLANES * (WW / TW) * (HH / TH))  // 12288
#define NTHREADS 256
#define NSTAGE (IN_H * 20)        // 520 staging granules
#define NITEMS1 (HALO_W * 4)      // 296 first-pass items (col, 4-row group)
#define TOTAL_ELEMS (PLANES * HH * WW)

typedef _Float16 half2v __attribute__((ext_vector_type(2)));
typedef float float2v __attribute__((ext_vector_type(2)));

constexpr float G_[11] = {
    1.4867195147342977e-06f, 1.3383022576488537e-04f, 4.4318484119380075e-03f,
    5.3990966513188063e-02f, 2.4197072451914337e-01f, 3.9894228040143270e-01f,
    2.4197072451914337e-01f, 5.3990966513188063e-02f, 4.4318484119380075e-03f,
    1.3383022576488537e-04f, 1.4867195147342977e-06f};

__device__ __forceinline__ half2v u2h(uint32_t u) {
  return __builtin_bit_cast(half2v, u);
}
// RTN fp16 pack — unbiased (v4/v8 verified; RTZ pack is NOT safe, v7).
__device__ __forceinline__ uint32_t packrtn(float a, float b) {
  half2v h = {(_Float16)a, (_Float16)b};
  return __builtin_bit_cast(uint32_t, h);
}

__global__ __launch_bounds__(NTHREADS, 4) void ssim_tile_kernel(
    const float* __restrict__ pred, const float* __restrict__ targ,
    float* __restrict__ partial) {
  __shared__ __align__(16) float sp[IN_H][SW];     // 8.7 KB raw pred
  __shared__ __align__(16) float st[IN_H][SW];     // 8.7 KB raw targ
  __shared__ __align__(16) uint2 rbAB[TH][RBW];    // 9.5 KB {pk(p,t),pk(pp,tt)}
  __shared__ __align__(16) float rbC[TH][RBW];     // 4.75 KB vconv_pt f32
  __shared__ float wsums[4];

  const int tid = threadIdx.x;
  const int bid = blockIdx.x;
  const int plane = bid >> 8;
  const int tile = bid & 255;
  const int x0 = (tile & 7) * TW;
  const int y0 = (tile >> 3) * TH;
  const float* pp = pred + (size_t)plane * (HH * WW);
  const float* tp = targ + (size_t)plane * (HH * WW);

  // ---- Stage 0: stage raw halo (granule-aligned float4) ----
  if ((x0 >= 64) && (x0 <= 384) && (y0 >= 16) && (y0 <= 480)) {
    // interior: all addresses in-range, unconditional loads
    for (int i = tid; i < NSTAGE; i += NTHREADS) {
      const int r = i / 20;
      const int cg = i - r * 20;
      const int o = (y0 + r - RR) * WW + (x0 - 8 + cg * 4);
      *reinterpret_cast<float4*>(&sp[r][cg * 4]) =
          *reinterpret_cast<const float4*>(pp + o);
      *reinterpret_cast<float4*>(&st[r][cg * 4]) =
          *reinterpret_cast<const float4*>(tp + o);
    }
  } else {
    for (int i = tid; i < NSTAGE; i += NTHREADS) {
      const int r = i / 20;            // halo row 0..25
      const int cg = i - r * 20;       // granule 0..19
      const int gy = y0 + r - RR;
      const int gx = x0 - 8 + cg * 4;  // granule start, 16B aligned
      float4 pv = make_float4(0.f, 0.f, 0.f, 0.f);
      float4 tv = pv;
      if (gy >= 0 && gy < HH && gx >= 0 && gx <= WW - 4) {
        const int o = gy * WW + gx;
        pv = *reinterpret_cast<const float4*>(pp + o);
        tv = *reinterpret_cast<const float4*>(tp + o);
      }
      *reinterpret_cast<float4*>(&sp[r][cg * 4]) = pv;
      *reinterpret_cast<float4*>(&st[r][cg * 4]) = tv;
    }
  }
  __syncthreads();

  // ---- Pass 1: VERTICAL conv (taps 1..9); items = (halo col, 4 rows) ----
  for (int i = tid; i < NITEMS1; i += NTHREADS) {
    const int c = i % HALO_W;        // halo col 0..73
    const int rg = i / HALO_W;       // 0..3
    const int yb = rg * 4;           // output rows yb..yb+3
    const int sc = c + COFF;         // staged col

    // needed halo rows: yb+1 .. yb+12 (taps 1..9 over 4 outputs)
    float pv[12], tv[12];
#pragma unroll
    for (int m = 0; m < 12; ++m) {
      pv[m] = sp[yb + 1 + m][sc];
      tv[m] = st[yb + 1 + m][sc];
    }

    // Scatter: halo row q (1..12) feeds outputs j in [q-9, q-1] ∩ [0,3]
    // with weight G_[q-j].
    float2v s01[4] = {{0,0},{0,0},{0,0},{0,0}};
    float2v s23[4] = {{0,0},{0,0},{0,0},{0,0}};
    float s4[4] = {0,0,0,0};
#pragma unroll
    for (int q = 1; q <= 12; ++q) {
      const float a = pv[q - 1];
      const float b = tv[q - 1];
      const float2v av = {a, b};
      const float2v sq = av * av;      // v_pk_mul_f32
      const float ab = a * b;
#pragma unroll
      for (int j = 0; j < 4; ++j) {
        if (j < q - 9 || j > q - 1) continue;
        const float w = G_[q - j];
        const float2v w2 = {w, w};
        s01[j] = __builtin_elementwise_fma(w2, av, s01[j]);  // v_pk_fma_f32
        s23[j] = __builtin_elementwise_fma(w2, sq, s23[j]);
        s4[j] = fmaf(w, ab, s4[j]);
      }
    }

#pragma unroll
    for (int j = 0; j < 4; ++j) {
      uint2 u;
      u.x = packrtn(s01[j].x, s01[j].y);
      u.y = packrtn(s23[j].x, s23[j].y);
      rbAB[yb + j][c] = u;             // ds_write_b64, lanes->cols: clean
      rbC[yb + j][c] = s4[j];          // ds_write_b32: clean
    }
  }
  __syncthreads();

  // ---- Pass 2: HORIZONTAL conv (taps 1..9, packed f32) + SSIM map ----
  float lsum = 0.f;
  {
    const int m = tid & 15;          // col group 0..15
    const int y = tid >> 4;          // output row 0..15
    const int cb = m << 2;           // outputs cb..cb+3

    // window reads (same pattern as v14): 7 b128 (rbAB) + 4 b128 (rbC)
    uint2 qv[14];
#pragma unroll
    for (int h = 0; h < 7; ++h) {
      uint4 w = *reinterpret_cast<const uint4*>(&rbAB[y][cb + 2 * h]);
      qv[2*h]   = make_uint2(w.x, w.y);
      qv[2*h+1] = make_uint2(w.z, w.w);
    }
    float cv[16];
#pragma unroll
    for (int h = 0; h < 4; ++h) {
      *reinterpret_cast<float4*>(&cv[4*h]) =
          *reinterpret_cast<const float4*>(&rbC[y][cb + 4 * h]);
    }

    // unpack only the used window cols: qv[1..12]
    float2v fa[12], fb[12];          // fa[k] <-> halo col cb+1+k
#pragma unroll
    for (int k = 0; k < 12; ++k) {
      half2v ha = u2h(qv[k + 1].x), hb = u2h(qv[k + 1].y);
      fa[k] = float2v{(float)ha.x, (float)ha.y};
      fb[k] = float2v{(float)hb.x, (float)hb.y};
    }

    float2v accA[4], accB[4];
    float sC[4];
#pragma unroll
    for (int j = 0; j < 4; ++j) {
      float2v a = {0, 0}, b = {0, 0};
      float c = 0.f;
#pragma unroll
      for (int k = 0; k < 9; ++k) {   // taps 1..9
        const float w = G_[k + 1];
        const float2v w2 = {w, w};
        a = __builtin_elementwise_fma(w2, fa[j + k], a);
        b = __builtin_elementwise_fma(w2, fb[j + k], b);
        c = fmaf(w, cv[j + 1 + k], c);
      }
      accA[j] = a; accB[j] = b; sC[j] = c;
    }

    const float C1 = 1.0e-4f;
    const float C2 = 9.0e-4f;
#pragma unroll
    for (int j = 0; j < 4; ++j) {
      const float mu_x = accA[j].x;
      const float mu_y = accA[j].y;
      const float2v sv = __builtin_elementwise_fma(-accA[j], accA[j], accB[j]);
      const float sxy = sC[j] - mu_x * mu_y;
      const float num = (2.f * mu_x * mu_y + C1) * (2.f * sxy + C2);
      const float den = (mu_x * mu_x + mu_y * mu_y + C1) *
                        (fmaf(sv.x, sv.x, fmaf(sv.y, sv.y, C2)));
      lsum = fmaf(num, __builtin_amdgcn_rcpf(den), lsum);
    }
  }

  // ---- Block reduction -> partial[bid] ----
#pragma unroll
  for (int off = 32; off > 0; off >>= 1) lsum += __shfl_xor(lsum, off, 64);
  if ((tid & 63) == 0) wsums[tid >> 6] = lsum;
  __syncthreads();
  if (tid == 0)
    partial[bid] = (wsums[0] + wsums[1]) + (wsums[2] + wsums[3]);
}

__global__ __launch_bounds__(1024) void ssim_reduce_kernel(
    const float* __restrict__ partial, float* __restrict__ out) {
  float s = 0.f;
  for (int i = threadIdx.x; i < NBLOCKS; i += 1024) s += partial[i];
#pragma unroll
  for (int off = 32; off > 0; off >>= 1) s += __shfl_xor(s, off, 64);
  __shared__ float ws[16];
  if ((threadIdx.x & 63) == 0) ws[threadIdx.x >> 6] = s;
  __syncthreads();
  if (threadIdx.x == 0) {
    float t = 0.f;
#pragma unroll
    for (int i = 0; i < 16; ++i) t += ws[i];
    out[0] = t * (1.0f / (float)TOTAL_ELEMS);
  }
}

extern "C" void kernel_launch(void* const* d_in, const int* in_sizes, int n_in,
                              void* d_out, int out_size, void* d_ws,
                              size_t ws_size, hipStream_t stream) {
  const float* pred = (const float*)d_in[0];
  const float* targ = (const float*)d_in[1];
  float* out = (float*)d_out;
  float* partial = (float*)d_ws;

  ssim_tile_kernel<<<NBLOCKS, NTHREADS, 0, stream>>>(pred, targ, partial);
  ssim_reduce_kernel<<<1, 1024, 0, stream>>>(partial, out);
}

// Round 17
// 66.122 us; speedup vs baseline: 1.3199x; 1.1169x over previous
//
#include <hip/hip_runtime.h>
#include <stdint.h>

// SSIM fused kernel v17, MI355X (gfx950).
// v15/v16 post-mortem: op-count cuts that perturb LDS patterns regress;
// time is governed by LDS instruction count + access shape. v14 base.
// v17: TRANSPOSED raw staging. spT[col][row] (rows padded to 28) makes
// pass-1's 14-row vertical window CONTIGUOUS -> 8 ds_read_b128 replace 28
// ds_read_b32 per item (-20 DS instr, -15 VALU addr). Bank analysis:
//  - pass-1 reads / stage-0 b128 writes: lane stride 28 words -> banks
//    28l mod 32 = 8 disjoint 4-bank spans = all 32 banks, conflict-free.
//  - stage-0 global loads: 4 per-row b32 instr, 64 consecutive cols each,
//    fully coalesced.
// Full 11 taps restored (v16 truncation reverted -> absmax 0 expected).
// Pass-2, math, fp16-RTN rbAB + f32 rbC, 2-kernel mean: identical to v14.

#define HH 512
#define WW 512
#define PLANES 48
#define TW 64
#define TH 16
#define RR 5
#define KK 11
#define HALO_W 74                  // halo cols c=0..73, global x = x0-5+c
#define TRP 28                     // padded rows per staged col (26 used)
#define RBW 76                     // rb row stride
#define NBLOCKS (PLANES * (WW / TW) * (HH / TH))  // 12288
#define NTHREADS 256
#define NSTAGE (HALO_W * 7)       // 518 vertical granules (col, 4-row group)
#define NITEMS1 (HALO_W * 4)      // 296 pass-1 items (col, 4-row group)
#define TOTAL_ELEMS (PLANES * HH * WW)

typedef _Float16 half2v __attribute__((ext_vector_type(2)));
typedef float float2v __attribute__((ext_vector_type(2)));

constexpr float G_[KK] = {
    1.4867195147342977e-06f, 1.3383022576488537e-04f, 4.4318484119380075e-03f,
    5.3990966513188063e-02f, 2.4197072451914337e-01f, 3.9894228040143270e-01f,
    2.4197072451914337e-01f, 5.3990966513188063e-02f, 4.4318484119380075e-03f,
    1.3383022576488537e-04f, 1.4867195147342977e-06f};

__device__ __forceinline__ half2v u2h(uint32_t u) {
  return __builtin_bit_cast(half2v, u);
}
// RTN fp16 pack — unbiased (v4/v8 verified; RTZ pack is NOT safe, v7).
__device__ __forceinline__ uint32_t packrtn(float a, float b) {
  half2v h = {(_Float16)a, (_Float16)b};
  return __builtin_bit_cast(uint32_t, h);
}

__global__ __launch_bounds__(NTHREADS, 4) void ssim_tile_kernel(
    const float* __restrict__ pred, const float* __restrict__ targ,
    float* __restrict__ partial) {
  __shared__ __align__(16) float spT[HALO_W][TRP];  // 8.3 KB pred, col-major
  __shared__ __align__(16) float stT[HALO_W][TRP];  // 8.3 KB targ, col-major
  __shared__ __align__(16) uint2 rbAB[TH][RBW];     // 9.5 KB {pk(p,t),pk(pp,tt)}
  __shared__ __align__(16) float rbC[TH][RBW];      // 4.75 KB vconv_pt f32
  __shared__ float wsums[4];

  const int tid = threadIdx.x;
  const int bid = blockIdx.x;
  const int plane = bid >> 8;
  const int tile = bid & 255;
  const int x0 = (tile & 7) * TW;
  const int y0 = (tile >> 3) * TH;
  const float* pp = pred + (size_t)plane * (HH * WW);
  const float* tp = targ + (size_t)plane * (HH * WW);

  const bool interior = (x0 >= 64) && (x0 <= 384) && (y0 >= 16) && (y0 <= 480);

  // ---- Stage 0: transposed staging. Granule = (col c, rows 4rg..4rg+3).
  // Global loads: per row offset w, 64 lanes read 64 consecutive cols
  // (coalesced b32). LDS write: one b128 per array per granule, stride-28
  // lanes -> conflict-free.
  if (interior) {
    for (int i = tid; i < NSTAGE; i += NTHREADS) {
      const int c = i % HALO_W;       // halo col 0..73
      const int rg = i / HALO_W;      // 0..6 (rows 24..27 staged, unread tail)
      const float* pb = pp + (y0 - RR + 4 * rg) * WW + (x0 - RR + c);
      const float* tb = tp + (y0 - RR + 4 * rg) * WW + (x0 - RR + c);
      float4 pv, tv;
      pv.x = pb[0]; pv.y = pb[WW]; pv.z = pb[2 * WW]; pv.w = pb[3 * WW];
      tv.x = tb[0]; tv.y = tb[WW]; tv.z = tb[2 * WW]; tv.w = tb[3 * WW];
      *reinterpret_cast<float4*>(&spT[c][4 * rg]) = pv;
      *reinterpret_cast<float4*>(&stT[c][4 * rg]) = tv;
    }
  } else {
    for (int i = tid; i < NSTAGE; i += NTHREADS) {
      const int c = i % HALO_W;
      const int rg = i / HALO_W;
      const int gx = x0 - RR + c;
      const bool xok = (gx >= 0) && (gx < WW);
      float4 pv = make_float4(0.f, 0.f, 0.f, 0.f);
      float4 tv = pv;
      if (xok) {
#pragma unroll
        for (int w = 0; w < 4; ++w) {
          const int gy = y0 - RR + 4 * rg + w;
          if (gy >= 0 && gy < HH) {
            reinterpret_cast<float*>(&pv)[w] = pp[gy * WW + gx];
            reinterpret_cast<float*>(&tv)[w] = tp[gy * WW + gx];
          }
        }
      }
      *reinterpret_cast<float4*>(&spT[c][4 * rg]) = pv;
      *reinterpret_cast<float4*>(&stT[c][4 * rg]) = tv;
    }
  }
  __syncthreads();

  // ---- Pass 1: VERTICAL conv of 5 quantities; window = 4 contiguous b128 --
  for (int i = tid; i < NITEMS1; i += NTHREADS) {
    const int c = i % HALO_W;        // halo col 0..73
    const int rg = i / HALO_W;       // 0..3
    const int yb = rg * 4;           // output rows yb..yb+3; window yb..yb+13

    float pv[16], tv[16];
#pragma unroll
    for (int h = 0; h < 4; ++h) {
      *reinterpret_cast<float4*>(&pv[4 * h]) =
          *reinterpret_cast<const float4*>(&spT[c][yb + 4 * h]);
      *reinterpret_cast<float4*>(&tv[4 * h]) =
          *reinterpret_cast<const float4*>(&stT[c][yb + 4 * h]);
    }

    // Scatter: window row q (0..13) feeds outputs j in [q-10, q] ∩ [0,3]
    // with weight G_[q-j].
    float2v s01[4] = {{0,0},{0,0},{0,0},{0,0}};
    float2v s23[4] = {{0,0},{0,0},{0,0},{0,0}};
    float s4[4] = {0,0,0,0};
#pragma unroll
    for (int q = 0; q < 14; ++q) {
      const float a = pv[q];
      const float b = tv[q];
      const float2v av = {a, b};
      const float2v sq = av * av;      // v_pk_mul_f32
      const float ab = a * b;
#pragma unroll
      for (int j = 0; j < 4; ++j) {
        if (q < j || q > j + 10) continue;
        const float w = G_[q - j];
        const float2v w2 = {w, w};
        s01[j] = __builtin_elementwise_fma(w2, av, s01[j]);  // v_pk_fma_f32
        s23[j] = __builtin_elementwise_fma(w2, sq, s23[j]);
        s4[j] = fmaf(w, ab, s4[j]);
      }
    }

#pragma unroll
    for (int j = 0; j < 4; ++j) {
      uint2 u;
      u.x = packrtn(s01[j].x, s01[j].y);
      u.y = packrtn(s23[j].x, s23[j].y);
      rbAB[yb + j][c] = u;             // ds_write_b64, lanes->cols: clean
      rbC[yb + j][c] = s4[j];          // ds_write_b32: clean
    }
  }
  __syncthreads();

  // ---- Pass 2: HORIZONTAL conv (packed f32) + SSIM map; 256 items exact --
  float lsum = 0.f;
  {
    const int m = tid & 15;          // col group 0..15
    const int y = tid >> 4;          // output row 0..15
    const int cb = m << 2;           // window cols cb..cb+13 (outputs cb..cb+3)

    uint2 qv[14];
#pragma unroll
    for (int h = 0; h < 7; ++h) {
      uint4 w = *reinterpret_cast<const uint4*>(&rbAB[y][cb + 2 * h]);
      qv[2*h]   = make_uint2(w.x, w.y);
      qv[2*h+1] = make_uint2(w.z, w.w);
    }
    float cv[16];
#pragma unroll
    for (int h = 0; h < 4; ++h) {
      *reinterpret_cast<float4*>(&cv[4*h]) =
          *reinterpret_cast<const float4*>(&rbC[y][cb + 4 * h]);
    }

    float2v fa[14], fb[14];
#pragma unroll
    for (int k = 0; k < 14; ++k) {
      half2v ha = u2h(qv[k].x), hb = u2h(qv[k].y);
      fa[k] = float2v{(float)ha.x, (float)ha.y};
      fb[k] = float2v{(float)hb.x, (float)hb.y};
    }

    float2v accA[4], accB[4];
    float sC[4];
#pragma unroll
    for (int j = 0; j < 4; ++j) {
      float2v a = {0, 0}, b = {0, 0};
      float c = 0.f;
#pragma unroll
      for (int k = 0; k < KK; ++k) {
        const float2v w2 = {G_[k], G_[k]};
        a = __builtin_elementwise_fma(w2, fa[j + k], a);
        b = __builtin_elementwise_fma(w2, fb[j + k], b);
        c = fmaf(G_[k], cv[j + k], c);
      }
      accA[j] = a; accB[j] = b; sC[j] = c;
    }

    const float C1 = 1.0e-4f;
    const float C2 = 9.0e-4f;
#pragma unroll
    for (int j = 0; j < 4; ++j) {
      const float mu_x = accA[j].x;
      const float mu_y = accA[j].y;
      const float2v sv = __builtin_elementwise_fma(-accA[j], accA[j], accB[j]);
      const float sxy = sC[j] - mu_x * mu_y;
      const float num = (2.f * mu_x * mu_y + C1) * (2.f * sxy + C2);
      const float den = (mu_x * mu_x + mu_y * mu_y + C1) *
                        (fmaf(sv.x, sv.x, fmaf(sv.y, sv.y, C2)));
      lsum = fmaf(num, __builtin_amdgcn_rcpf(den), lsum);
    }
  }

  // ---- Block reduction -> partial[bid] ----
#pragma unroll
  for (int off = 32; off > 0; off >>= 1) lsum += __shfl_xor(lsum, off, 64);
  if ((tid & 63) == 0) wsums[tid >> 6] = lsum;
  __syncthreads();
  if (tid == 0)
    partial[bid] = (wsums[0] + wsums[1]) + (wsums[2] + wsums[3]);
}

__global__ __launch_bounds__(1024) void ssim_reduce_kernel(
    const float* __restrict__ partial, float* __restrict__ out) {
  float s = 0.f;
  for (int i = threadIdx.x; i < NBLOCKS; i += 1024) s += partial[i];
#pragma unroll
  for (int off = 32; off > 0; off >>= 1) s += __shfl_xor(s, off, 64);
  __shared__ float ws[16];
  if ((threadIdx.x & 63) == 0) ws[threadIdx.x >> 6] = s;
  __syncthreads();
  if (threadIdx.x == 0) {
    float t = 0.f;
#pragma unroll
    for (int i = 0; i < 16; ++i) t += ws[i];
    out[0] = t * (1.0f / (float)TOTAL_ELEMS);
  }
}

extern "C" void kernel_launch(void* const* d_in, const int* in_sizes, int n_in,
                              void* d_out, int out_size, void* d_ws,
                              size_t ws_size, hipStream_t stream) {
  const float* pred = (const float*)d_in[0];
  const float* targ = (const float*)d_in[1];
  float* out = (float*)d_out;
  float* partial = (float*)d_ws;

  ssim_tile_kernel<<<NBLOCKS, NTHREADS, 0, stream>>>(pred, targ, partial);
  ssim_reduce_kernel<<<1, 1024, 0, stream>>>(partial, out);
}